// Round 1
// 486.910 us; speedup vs baseline: 1.1140x; 1.1140x over previous
//
#include <hip/hip_runtime.h>
#include <stdint.h>

typedef __attribute__((ext_vector_type(8))) short bf16x8;   // 8 bf16 in 4 VGPRs
typedef __attribute__((ext_vector_type(4))) float f32x4;    // MFMA C/D frag
typedef __attribute__((ext_vector_type(4))) unsigned short u16x4;

__device__ __forceinline__ unsigned short f2bf(float f) {
  uint32_t u = __builtin_bit_cast(uint32_t, f);
  uint32_t r = (u + 0x7FFFu + ((u >> 16) & 1u)) >> 16;  // round-to-nearest-even
  return (unsigned short)r;
}

// ---------------- Fused prep: dequant blocks first, then cvt blocks ----------
// (unchanged from R-prev: verified; counters for it not yet visible in top-5)
__global__ __launch_bounds__(256) void prep_kernel(
    const float4* __restrict__ x, u16x4* __restrict__ xb, int n4,
    const float* __restrict__ centroids, const int* __restrict__ labels,
    const float* __restrict__ scale, uint32_t* __restrict__ BtP,
    int K, int G, int dqBlocksX, int dqBlocks) {
  const int bid = blockIdx.x;
  if (bid < dqBlocks) {
    const int bx = bid % dqBlocksX;           // kpair block (pow2 count)
    const int by = bid / dqBlocksX;           // group quad
    const int p  = bx * 256 + threadIdx.x;    // kpair index, 0..K/2-1
    const int k0 = 2 * p;
    const int g0 = by * 4;
    const int Kh = K >> 1;

    const float rs0 = 1.0f / fmaxf(scale[k0], 1e-8f);
    const float rs1 = 1.0f / fmaxf(scale[k0 + 1], 1e-8f);
    const int4 La = *(const int4*)(labels + (size_t)k0 * G + g0);
    const int4 Lb = *(const int4*)(labels + (size_t)(k0 + 1) * G + g0);
    const int la[4] = {La.x, La.y, La.z, La.w};
    const int lb[4] = {Lb.x, Lb.y, Lb.z, Lb.w};

    float4 a0[4], a1[4], b0[4], b1[4];
#pragma unroll
    for (int g = 0; g < 4; ++g) {             // 16 independent gathers -> MLP
      const float4* pa = (const float4*)(centroids + (size_t)la[g] * 8);
      const float4* pb = (const float4*)(centroids + (size_t)lb[g] * 8);
      a0[g] = pa[0]; a1[g] = pa[1];
      b0[g] = pb[0]; b1[g] = pb[1];
    }

#pragma unroll
    for (int g = 0; g < 4; ++g) {
      const float fa[8] = {a0[g].x, a0[g].y, a0[g].z, a0[g].w,
                           a1[g].x, a1[g].y, a1[g].z, a1[g].w};
      const float fb[8] = {b0[g].x, b0[g].y, b0[g].z, b0[g].w,
                           b1[g].x, b1[g].y, b1[g].z, b1[g].w};
      const size_t nbase = (size_t)((g0 + g) * 8) * (size_t)Kh + (size_t)p;
#pragma unroll
      for (int j = 0; j < 8; ++j) {
        uint32_t v = (uint32_t)f2bf(fa[j] * rs0) |
                     ((uint32_t)f2bf(fb[j] * rs1) << 16);
        BtP[nbase + (size_t)j * Kh] = v;
      }
    }
  } else {
    const int i = (bid - dqBlocks) * 256 + threadIdx.x;
    if (i >= n4) return;
    float4 v = x[i];
    u16x4 o;
    o.x = f2bf(v.x); o.y = f2bf(v.y); o.z = f2bf(v.z); o.w = f2bf(v.w);
    xb[i] = o;
  }
}

// ---------------- 256x256 8-phase bf16 GEMM + bias (m201 template port) ------
// 512 threads = 8 waves (2M x 4N), per-wave 128x64 out = 8x4 frags of 16x16.
// K-tile = 64 split in two 32-k halves; LDS sA/sB[2 dbuf][2 khalf][256][32].
// Staging: global_load_lds w=16, linear LDS dest, inverse-swizzled global src
// (chunk q ^= (row>>1)&3); ds_read applies the same XOR -> conflict-free-ish.
// vmcnt(4) only at phases 4 and 8 (counted, never 0 mid-loop) = T3+T4.
// setprio(1) around each 16-MFMA cluster = T5. Bijective XCD swizzle = T1.

#define STG_A(t, ks) do {                                                          \
    const unsigned short* _s0 = gA0 + (size_t)(t) * 64 + (ks) * 32;                \
    char* _d = (char*)sA + ((t) & 1) * 32768 + (ks) * 16384 + (w << 10);           \
    __builtin_amdgcn_global_load_lds((const __attribute__((address_space(1))) void*)_s0, \
                                     (__attribute__((address_space(3))) void*)_d, 16, 0, 0); \
    __builtin_amdgcn_global_load_lds((const __attribute__((address_space(1))) void*)(_s0 + ((size_t)K << 7)), \
                                     (__attribute__((address_space(3))) void*)(_d + 8192), 16, 0, 0); \
  } while (0)

#define STG_B(t, ks) do {                                                          \
    const unsigned short* _s0 = gB0 + (size_t)(t) * 64 + (ks) * 32;                \
    char* _d = (char*)sB + ((t) & 1) * 32768 + (ks) * 16384 + (w << 10);           \
    __builtin_amdgcn_global_load_lds((const __attribute__((address_space(1))) void*)_s0, \
                                     (__attribute__((address_space(3))) void*)_d, 16, 0, 0); \
    __builtin_amdgcn_global_load_lds((const __attribute__((address_space(1))) void*)(_s0 + ((size_t)K << 7)), \
                                     (__attribute__((address_space(3))) void*)(_d + 8192), 16, 0, 0); \
  } while (0)

#define LDA4(mh, ks, buf) do {                                                     \
    const char* _p = pA + (buf) * 32768 + (ks) * 16384 + (mh) * 4096 + aoff;       \
    af[0] = *(const bf16x8*)_p;          af[1] = *(const bf16x8*)(_p + 1024);      \
    af[2] = *(const bf16x8*)(_p + 2048); af[3] = *(const bf16x8*)(_p + 3072);      \
  } while (0)

#define LDB4(ks, buf) do {                                                         \
    const char* _p = pB + (buf) * 32768 + (ks) * 16384 + boff;                     \
    bq[0] = *(const bf16x8*)_p;          bq[1] = *(const bf16x8*)(_p + 1024);      \
    bq[2] = *(const bf16x8*)(_p + 2048); bq[3] = *(const bf16x8*)(_p + 3072);      \
  } while (0)

#define MFMA16(off) do {                                                           \
    _Pragma("unroll")                                                              \
    for (int _mi = 0; _mi < 4; ++_mi) {                                            \
      _Pragma("unroll")                                                            \
      for (int _ni = 0; _ni < 4; ++_ni)                                            \
        acc[(off) + _mi * 4 + _ni] = __builtin_amdgcn_mfma_f32_16x16x32_bf16(      \
            af[_mi], bq[_ni], acc[(off) + _mi * 4 + _ni], 0, 0, 0);                \
    } } while (0)

#define PHASE_TAIL(off) do {                                                       \
    asm volatile("" ::: "memory");                                                 \
    __builtin_amdgcn_s_barrier();                                                  \
    __builtin_amdgcn_s_setprio(1);                                                 \
    MFMA16(off);                                                                   \
    __builtin_amdgcn_s_setprio(0);                                                 \
    __builtin_amdgcn_sched_barrier(0);                                             \
    asm volatile("" ::: "memory");                                                 \
    __builtin_amdgcn_s_barrier();                                                  \
    asm volatile("" ::: "memory");                                                 \
  } while (0)

__global__ __launch_bounds__(512, 2) void gemm256_kernel(
    const unsigned short* __restrict__ A,   // [M][K] bf16
    const unsigned short* __restrict__ B,   // [N][K] bf16 (B^T layout)
    const float* __restrict__ bias,         // [N]
    float* __restrict__ C,                  // [M][N] fp32
    int M, int N, int K) {
  __shared__ __align__(16) unsigned short sA[2][2][256][32];  // 64 KB
  __shared__ __align__(16) unsigned short sB[2][2][256][32];  // 64 KB

  const int tid  = threadIdx.x;
  const int w    = tid >> 6;        // wave 0..7
  const int lane = tid & 63;
  const int ln   = lane & 15;
  const int quad = lane >> 4;
  const int wm   = w >> 2;          // 2x4 wave grid; each wave 128x64 out
  const int wn   = w & 3;

  // T1: bijective XCD swizzle (m204)
  const int nbx = N >> 8;
  const int nwg = gridDim.x;
  const int xcd = blockIdx.x & 7, loc = blockIdx.x >> 3;
  const int qq = nwg >> 3, rr = nwg & 7;
  const int wg = (xcd < rr ? xcd * (qq + 1) : rr * (qq + 1) + (xcd - rr) * qq) + loc;
  const int by = wg / nbx, bx = wg % nbx;
  const int m0 = by << 8, n0 = bx << 8;

  // staging source: thread -> (row r0 / r0+128, swizzled 16B chunk qs)
  const int r0 = (w << 4) + (lane >> 2);                 // 0..127
  const int qs = (lane & 3) ^ ((r0 >> 1) & 3);          // same for row r0+128
  const unsigned short* gA0 = A + (size_t)(m0 + r0) * K + qs * 8;
  const unsigned short* gB0 = B + (size_t)(n0 + r0) * K + qs * 8;

  // ds_read: byte = half_base + row*64 + ((quad ^ ((row>>1)&3))<<4)
  const char* pA = (const char*)sA;
  const char* pB = (const char*)sB;
  const int qsw  = (quad ^ ((ln >> 1) & 3)) << 4;
  const int aoff = (wm << 13) + (ln << 6) + qsw;        // wm*128 rows + ln rows
  const int boff = (wn << 12) + (ln << 6) + qsw;        // wn*64 rows + ln rows

  f32x4 acc[32];
#pragma unroll
  for (int i = 0; i < 32; ++i) acc[i] = (f32x4){0.f, 0.f, 0.f, 0.f};
  bf16x8 af[4], bq[4];

  // Prologue: tile0 complete + tile1 k-half0; keep last 4 loads in flight.
  STG_A(0, 0); STG_B(0, 0);
  STG_A(0, 1); STG_B(0, 1);
  STG_A(1, 0); STG_B(1, 0);
  asm volatile("s_waitcnt vmcnt(4)" ::: "memory");
  __builtin_amdgcn_s_barrier();
  asm volatile("" ::: "memory");

  const int NI = K >> 7;            // 2 K-tiles (2x64) per iteration
  for (int i = 0; i < NI; ++i) {
    const int t0 = i << 1, t1 = t0 + 1;
    const bool nl = (i + 1 < NI);

    // P1: (t0,k0,mh0) | stage A k1(t1)  [buf1 k1 last read prev P7/P8]
    LDB4(0, 0); LDA4(0, 0, 0);
    STG_A(t1, 1);
    PHASE_TAIL(0);
    // P2: (t0,k0,mh1) | stage B k1(t1)
    LDA4(1, 0, 0);
    STG_B(t1, 1);
    PHASE_TAIL(16);
    // P3: (t0,k1,mh0) | stage A k0(t0+2)  [buf0 k0 last read P1/P2]
    LDB4(1, 0); LDA4(0, 1, 0);
    if (nl) STG_A(t0 + 2, 0);
    PHASE_TAIL(0);
    // P4: (t0,k1,mh1) | stage B k0(t0+2); counted vmcnt -> tile t1 landed
    LDA4(1, 1, 0);
    if (nl) { STG_B(t0 + 2, 0); asm volatile("s_waitcnt vmcnt(4)" ::: "memory"); }
    else    {                   asm volatile("s_waitcnt vmcnt(0)" ::: "memory"); }
    PHASE_TAIL(16);
    // P5: (t1,k0,mh0) | stage A k1(t0+2)  [buf0 k1 last read P3/P4]
    LDB4(0, 1); LDA4(0, 0, 1);
    if (nl) STG_A(t0 + 2, 1);
    PHASE_TAIL(0);
    // P6: (t1,k0,mh1) | stage B k1(t0+2)
    LDA4(1, 0, 1);
    if (nl) STG_B(t0 + 2, 1);
    PHASE_TAIL(16);
    // P7: (t1,k1,mh0) | stage A k0(t0+3)  [buf1 k0 last read P5/P6]
    LDB4(1, 1); LDA4(0, 1, 1);
    if (nl) STG_A(t0 + 3, 0);
    PHASE_TAIL(0);
    // P8: (t1,k1,mh1) | stage B k0(t0+3); counted vmcnt -> tile t0+2 landed
    LDA4(1, 1, 1);
    if (nl) { STG_B(t0 + 3, 0); asm volatile("s_waitcnt vmcnt(4)" ::: "memory"); }
    PHASE_TAIL(16);
  }

  // Epilogue: C/D layout col = lane&15, row = quad*4 + reg (verified)
#pragma unroll
  for (int ni = 0; ni < 4; ++ni) {
    const int n = n0 + wn * 64 + ni * 16 + ln;
    const float bv = bias[n];
#pragma unroll
    for (int MI = 0; MI < 8; ++MI) {
      const int mb = m0 + wm * 128 + MI * 16 + quad * 4;
#pragma unroll
      for (int r = 0; r < 4; ++r)
        C[(size_t)(mb + r) * N + n] = acc[MI * 4 + ni][r] + bv;
    }
  }
}

// ---------------- Fallback (shape assumptions violated): correct but slow ----
__global__ __launch_bounds__(256) void fallback_kernel(
    const float* __restrict__ x, const float* __restrict__ centroids,
    const int* __restrict__ labels, const float* __restrict__ scale,
    const float* __restrict__ bias, float* __restrict__ out,
    int M, int N, int K, int G) {
  int idx = blockIdx.x * 256 + threadIdx.x;
  if (idx >= M * N) return;
  int m = idx / N, n = idx % N;
  float acc = 0.f;
  for (int k = 0; k < K; ++k) {
    int lab = labels[(size_t)k * G + (n >> 3)];
    float wv = centroids[(size_t)lab * 8 + (n & 7)] / fmaxf(scale[k], 1e-8f);
    acc += x[(size_t)m * K + k] * wv;
  }
  out[idx] = acc + bias[n];
}

extern "C" void kernel_launch(void* const* d_in, const int* in_sizes, int n_in,
                              void* d_out, int out_size, void* d_ws, size_t ws_size,
                              hipStream_t stream) {
  const float* x         = (const float*)d_in[0];
  const float* centroids = (const float*)d_in[1];
  const int*   labels    = (const int*)d_in[2];
  const float* scale     = (const float*)d_in[3];
  const float* bias      = (const float*)d_in[4];
  float* out = (float*)d_out;

  const int in_f  = in_sizes[3];         // 4096 (K)
  const int out_f = in_sizes[4];         // 4096 (N)
  const int M     = in_sizes[0] / in_f;  // 8192
  const int G     = in_sizes[2] / in_f;  // 512 groups per column
  const int K = in_f, N = out_f;

  size_t need = (size_t)M * K * 2 + (size_t)N * K * 2;  // ~100.7 MB
  bool ok = (ws_size >= need) && (K % 512 == 0) && (G % 4 == 0) &&
            (M % 256 == 0) && (N % 256 == 0) && (K % 128 == 0) &&
            (M * K % 1024 == 0);
  if (!ok) {
    int total = M * N;
    fallback_kernel<<<dim3((total + 255) / 256), 256, 0, stream>>>(
        x, centroids, labels, scale, bias, out, M, N, K, G);
    return;
  }

  unsigned short* Xb = (unsigned short*)d_ws;           // [M][K] bf16
  unsigned short* Bt = Xb + (size_t)M * K;              // [N][K] bf16

  const int n4 = (M * K) / 4;
  const int dqBlocksX = (K / 2) / 256;                  // 8
  const int dqBlocks  = dqBlocksX * (G / 4);            // 1024
  const int cvtBlocks = (n4 + 255) / 256;               // 8192
  prep_kernel<<<dim3(dqBlocks + cvtBlocks), 256, 0, stream>>>(
      (const float4*)x, (u16x4*)Xb, n4, centroids, labels, scale,
      (uint32_t*)Bt, K, G, dqBlocksX, dqBlocks);

  const int nwg = (M / 256) * (N / 256);                // 512
  gemm256_kernel<<<dim3(nwg), dim3(512), 0, stream>>>(Xb, Bt, bias, out, M, N, K);
}